// Round 1
// baseline (719.862 us; speedup 1.0000x reference)
//
#include <hip/hip_runtime.h>
#include <hip/hip_bf16.h>
#include <stdint.h>

#define N_EXPERTS 8
#define D_MODEL   1024
#define D_FF      4096
#define T_TOKENS  2048
#define MT        32
#define MAXT      72      // worst-case sum of ceil(cnt_e/MT): 64 + 8
#define KPAD      40      // LDS k-stride (bf16 elems); 80B rows -> conflict-free-ish b128

typedef __attribute__((ext_vector_type(8))) short bf16x8;
typedef __attribute__((ext_vector_type(4))) float f32x4;

__device__ __forceinline__ short f2bf(float f) {
    union { float f; uint32_t u; } v; v.f = f;
    uint32_t u = v.u;
    uint32_t r = (u + 0x7fffu + ((u >> 16) & 1u)) >> 16;
    return (short)r;
}

// ---------------- routing ----------------

__global__ void moe_count(const int* __restrict__ idx, int* __restrict__ counts) {
    int t = blockIdx.x * blockDim.x + threadIdx.x;
    if (t < T_TOKENS) atomicAdd(&counts[idx[t]], 1);
}

__global__ void moe_scan(const int* __restrict__ counts, int* __restrict__ offsets,
                         int* __restrict__ ntiles, int* __restrict__ tile_e,
                         int* __restrict__ tile_p0, int* __restrict__ tile_end) {
    if (threadIdx.x == 0 && blockIdx.x == 0) {
        int off = 0, nt = 0;
        for (int e = 0; e < N_EXPERTS; ++e) {
            offsets[e] = off;
            int c = counts[e];
            int end = off + c;
            for (int i = 0; i < c; i += MT) {
                tile_e[nt] = e;
                tile_p0[nt] = off + i;
                tile_end[nt] = end;
                ++nt;
            }
            off = end;
        }
        offsets[N_EXPERTS] = off;
        *ntiles = nt;
    }
}

// one block per token: claim a permuted row slot, gather+convert x row to bf16
__global__ void moe_gather(const float* __restrict__ x, const int* __restrict__ idx,
                           const int* __restrict__ offsets, int* __restrict__ cursor,
                           int* __restrict__ tok_of_row, short* __restrict__ Xg) {
    __shared__ int sp;
    int t = blockIdx.x;
    if (threadIdx.x == 0) {
        int e = idx[t];
        int p = offsets[e] + atomicAdd(&cursor[e], 1);
        tok_of_row[p] = t;
        sp = p;
    }
    __syncthreads();
    int p = sp;
    const float4* src = (const float4*)(x + (size_t)t * D_MODEL);
    uint2* dst = (uint2*)(Xg + (size_t)p * D_MODEL);
    int i = threadIdx.x;                       // D_MODEL/4 == 256 == blockDim
    float4 v = src[i];
    uint2 o;
    o.x = (uint32_t)(uint16_t)f2bf(v.x) | ((uint32_t)(uint16_t)f2bf(v.y) << 16);
    o.y = (uint32_t)(uint16_t)f2bf(v.z) | ((uint32_t)(uint16_t)f2bf(v.w) << 16);
    dst[i] = o;
}

// ---------------- GEMM1: gate/up + SwiGLU -> h (bf16) ----------------
// grid: (D_FF/64, MAXT), block 256 (4 waves). Block tile: M=32, N=64 (both mats).
// Wave w handles n-slice [16w,16w+16) for BOTH gate and up.

__launch_bounds__(256)
__global__ void moe_gemm1(const float* __restrict__ wg, const float* __restrict__ wu,
                          const short* __restrict__ Xg, short* __restrict__ h,
                          const int* __restrict__ tile_e, const int* __restrict__ tile_p0,
                          const int* __restrict__ tile_end, const int* __restrict__ ntiles) {
    int ti = blockIdx.y;
    if (ti >= *ntiles) return;
    int e = tile_e[ti], p0 = tile_p0[ti], pend = tile_end[ti];
    int n0 = blockIdx.x * 64;

    __shared__ short Bg[64][KPAD];
    __shared__ short Bu[64][KPAD];

    int tid = threadIdx.x;
    int nl = tid & 63, kc = tid >> 6;          // staging role: n-lane, k-chunk
    int lane = tid & 63, w = tid >> 6;         // compute role
    int col = lane & 15, quad = lane >> 4;

    const float* wgb = wg + (size_t)e * D_MODEL * D_FF + n0 + nl;
    const float* wub = wu + (size_t)e * D_MODEL * D_FF + n0 + nl;

    int row0 = p0 + col;        if (row0 > T_TOKENS - 1) row0 = T_TOKENS - 1;
    int row1 = p0 + 16 + col;   if (row1 > T_TOKENS - 1) row1 = T_TOKENS - 1;
    const short* a0p = Xg + (size_t)row0 * D_MODEL + quad * 8;
    const short* a1p = Xg + (size_t)row1 * D_MODEL + quad * 8;

    f32x4 accg0 = {0,0,0,0}, accg1 = {0,0,0,0};
    f32x4 accu0 = {0,0,0,0}, accu1 = {0,0,0,0};

    for (int k0 = 0; k0 < D_MODEL; k0 += 32) {
        {   // stage W tiles (transpose fp32 [k][n] -> LDS bf16 [n][k])
            const float* g = wgb + (size_t)(k0 + kc * 8) * D_FF;
            const float* u = wub + (size_t)(k0 + kc * 8) * D_FF;
            bf16x8 pg, pu;
#pragma unroll
            for (int j = 0; j < 8; ++j) {
                pg[j] = f2bf(g[(size_t)j * D_FF]);
                pu[j] = f2bf(u[(size_t)j * D_FF]);
            }
            *(bf16x8*)&Bg[nl][kc * 8] = pg;
            *(bf16x8*)&Bu[nl][kc * 8] = pu;
        }
        __syncthreads();
        bf16x8 a0 = *(const bf16x8*)(a0p + k0);
        bf16x8 a1 = *(const bf16x8*)(a1p + k0);
        bf16x8 bg = *(const bf16x8*)&Bg[w * 16 + col][quad * 8];
        bf16x8 bu = *(const bf16x8*)&Bu[w * 16 + col][quad * 8];
        accg0 = __builtin_amdgcn_mfma_f32_16x16x32_bf16(a0, bg, accg0, 0, 0, 0);
        accg1 = __builtin_amdgcn_mfma_f32_16x16x32_bf16(a1, bg, accg1, 0, 0, 0);
        accu0 = __builtin_amdgcn_mfma_f32_16x16x32_bf16(a0, bu, accu0, 0, 0, 0);
        accu1 = __builtin_amdgcn_mfma_f32_16x16x32_bf16(a1, bu, accu1, 0, 0, 0);
        __syncthreads();
    }

    // epilogue: h = silu(gate) * up, masked rows
    int ncol = n0 + w * 16 + col;
#pragma unroll
    for (int r = 0; r < 4; ++r) {
        int m0r = p0 + quad * 4 + r;
        if (m0r < pend) {
            float gv = accg0[r], uv = accu0[r];
            float hv = (gv / (1.f + __expf(-gv))) * uv;
            h[(size_t)m0r * D_FF + ncol] = f2bf(hv);
        }
        int m1r = p0 + 16 + quad * 4 + r;
        if (m1r < pend) {
            float gv = accg1[r], uv = accu1[r];
            float hv = (gv / (1.f + __expf(-gv))) * uv;
            h[(size_t)m1r * D_FF + ncol] = f2bf(hv);
        }
    }
}

// ---------------- GEMM2: out = h @ Wd, scatter rows ----------------
// grid: (D_MODEL/64, MAXT), block 256 (4 waves). Block tile: M=32, N=64.

__launch_bounds__(256)
__global__ void moe_gemm2(const float* __restrict__ wd, const short* __restrict__ h,
                          const int* __restrict__ tok_of_row, float* __restrict__ out,
                          const int* __restrict__ tile_e, const int* __restrict__ tile_p0,
                          const int* __restrict__ tile_end, const int* __restrict__ ntiles) {
    int ti = blockIdx.y;
    if (ti >= *ntiles) return;
    int e = tile_e[ti], p0 = tile_p0[ti], pend = tile_end[ti];
    int d0 = blockIdx.x * 64;

    __shared__ short Bd[64][KPAD];

    int tid = threadIdx.x;
    int nl = tid & 63, kc = tid >> 6;
    int lane = tid & 63, w = tid >> 6;
    int col = lane & 15, quad = lane >> 4;

    const float* wb = wd + (size_t)e * D_FF * D_MODEL + d0 + nl;

    int row0 = p0 + col;        if (row0 > T_TOKENS - 1) row0 = T_TOKENS - 1;
    int row1 = p0 + 16 + col;   if (row1 > T_TOKENS - 1) row1 = T_TOKENS - 1;
    const short* a0p = h + (size_t)row0 * D_FF + quad * 8;
    const short* a1p = h + (size_t)row1 * D_FF + quad * 8;

    f32x4 acc0 = {0,0,0,0}, acc1 = {0,0,0,0};

    for (int k0 = 0; k0 < D_FF; k0 += 32) {
        {
            const float* p = wb + (size_t)(k0 + kc * 8) * D_MODEL;
            bf16x8 pk;
#pragma unroll
            for (int j = 0; j < 8; ++j) pk[j] = f2bf(p[(size_t)j * D_MODEL]);
            *(bf16x8*)&Bd[nl][kc * 8] = pk;
        }
        __syncthreads();
        bf16x8 a0 = *(const bf16x8*)(a0p + k0);
        bf16x8 a1 = *(const bf16x8*)(a1p + k0);
        bf16x8 b  = *(const bf16x8*)&Bd[w * 16 + col][quad * 8];
        acc0 = __builtin_amdgcn_mfma_f32_16x16x32_bf16(a0, b, acc0, 0, 0, 0);
        acc1 = __builtin_amdgcn_mfma_f32_16x16x32_bf16(a1, b, acc1, 0, 0, 0);
        __syncthreads();
    }

    int dcol = d0 + w * 16 + col;
#pragma unroll
    for (int r = 0; r < 4; ++r) {
        int m0r = p0 + quad * 4 + r;
        if (m0r < pend) {
            int t = tok_of_row[m0r];
            out[(size_t)t * D_MODEL + dcol] = acc0[r];
        }
        int m1r = p0 + 16 + quad * 4 + r;
        if (m1r < pend) {
            int t = tok_of_row[m1r];
            out[(size_t)t * D_MODEL + dcol] = acc1[r];
        }
    }
}

// ---------------- launch ----------------

extern "C" void kernel_launch(void* const* d_in, const int* in_sizes, int n_in,
                              void* d_out, int out_size, void* d_ws, size_t ws_size,
                              hipStream_t stream) {
    (void)in_sizes; (void)n_in; (void)out_size; (void)ws_size;
    const float* x   = (const float*)d_in[0];
    const int*   idx = (const int*)d_in[1];
    const float* wg  = (const float*)d_in[2];
    const float* wu  = (const float*)d_in[3];
    const float* wd  = (const float*)d_in[4];
    float* out = (float*)d_out;

    int* ws_i       = (int*)d_ws;
    int* counts     = ws_i;            // 8
    int* cursor     = ws_i + 8;        // 8
    int* offsets    = ws_i + 16;       // 9
    int* ntiles     = ws_i + 25;       // 1
    int* tile_e     = ws_i + 32;       // 72
    int* tile_p0    = ws_i + 104;      // 72
    int* tile_end   = ws_i + 176;      // 72
    int* tok_of_row = ws_i + 256;      // 2048

    short* Xg = (short*)((char*)d_ws + 16384);
    short* h  = (short*)((char*)d_ws + 16384 + (size_t)T_TOKENS * D_MODEL * 2);

    hipMemsetAsync(d_ws, 0, 1024, stream);
    moe_count<<<dim3((T_TOKENS + 255) / 256), 256, 0, stream>>>(idx, counts);
    moe_scan<<<dim3(1), 64, 0, stream>>>(counts, offsets, ntiles, tile_e, tile_p0, tile_end);
    moe_gather<<<dim3(T_TOKENS), 256, 0, stream>>>(x, idx, offsets, cursor, tok_of_row, Xg);
    moe_gemm1<<<dim3(D_FF / 64, MAXT), 256, 0, stream>>>(wg, wu, Xg, h,
                                                         tile_e, tile_p0, tile_end, ntiles);
    moe_gemm2<<<dim3(D_MODEL / 64, MAXT), 256, 0, stream>>>(wd, h, tok_of_row, out,
                                                            tile_e, tile_p0, tile_end, ntiles);
}

// Round 2
// 566.025 us; speedup vs baseline: 1.2718x; 1.2718x over previous
//
#include <hip/hip_runtime.h>
#include <hip/hip_bf16.h>
#include <stdint.h>

#define N_EXPERTS 8
#define D_MODEL   1024
#define D_FF      4096
#define T_TOKENS  2048
#define MT        128
#define MAXT      24      // worst-case sum of ceil(cnt_e/MT): 16 + 7, padded
#define KPAD      40      // LDS k-stride (bf16 elems); 80B rows, 16B-aligned b128

typedef __attribute__((ext_vector_type(8))) short bf16x8;
typedef __attribute__((ext_vector_type(4))) float f32x4;

__device__ __forceinline__ short f2bf(float f) {
    union { float f; uint32_t u; } v; v.f = f;
    uint32_t u = v.u;
    uint32_t r = (u + 0x7fffu + ((u >> 16) & 1u)) >> 16;
    return (short)r;
}

__device__ __forceinline__ uint32_t pack2bf(float a, float b) {
    __hip_bfloat162 h = __float22bfloat162_rn(make_float2(a, b));
    return *(uint32_t*)&h;
}

// ---------------- routing ----------------

__global__ void moe_count(const int* __restrict__ idx, int* __restrict__ counts) {
    int t = blockIdx.x * blockDim.x + threadIdx.x;
    if (t < T_TOKENS) atomicAdd(&counts[idx[t]], 1);
}

__global__ void moe_scan(const int* __restrict__ counts, int* __restrict__ offsets,
                         int* __restrict__ ntiles, int* __restrict__ tile_e,
                         int* __restrict__ tile_p0, int* __restrict__ tile_end) {
    if (threadIdx.x == 0 && blockIdx.x == 0) {
        int off = 0, nt = 0;
        for (int e = 0; e < N_EXPERTS; ++e) {
            offsets[e] = off;
            int c = counts[e];
            int end = off + c;
            for (int i = 0; i < c; i += MT) {
                tile_e[nt] = e;
                tile_p0[nt] = off + i;
                tile_end[nt] = end;
                ++nt;
            }
            off = end;
        }
        offsets[N_EXPERTS] = off;
        *ntiles = nt;
    }
}

// one block per token: claim a permuted row slot, gather+convert x row to bf16
__global__ void moe_gather(const float* __restrict__ x, const int* __restrict__ idx,
                           const int* __restrict__ offsets, int* __restrict__ cursor,
                           int* __restrict__ tok_of_row, short* __restrict__ Xg) {
    __shared__ int sp;
    int t = blockIdx.x;
    if (threadIdx.x == 0) {
        int e = idx[t];
        int p = offsets[e] + atomicAdd(&cursor[e], 1);
        tok_of_row[p] = t;
        sp = p;
    }
    __syncthreads();
    int p = sp;
    const float4* src = (const float4*)(x + (size_t)t * D_MODEL);
    uint2* dst = (uint2*)(Xg + (size_t)p * D_MODEL);
    int i = threadIdx.x;                       // D_MODEL/4 == 256 == blockDim
    float4 v = src[i];
    uint2 o;
    o.x = pack2bf(v.x, v.y);
    o.y = pack2bf(v.z, v.w);
    dst[i] = o;
}

// ---------------- GEMM1: gate/up + SwiGLU -> h (bf16) ----------------
// grid: (D_FF/64, MAXT), block 256 (4 waves). Block tile: M=128, N=64 (both mats).
// Wave w owns M-rows [32w, 32w+32); covers all 64 N columns for gate AND up.
// Per k-step(32): staging 2*64*32 elems (16 ld+cvt/thread) feeds 64 MFMAs/block.

__launch_bounds__(256)
__global__ void moe_gemm1(const float* __restrict__ wg, const float* __restrict__ wu,
                          const short* __restrict__ Xg, short* __restrict__ h,
                          const int* __restrict__ tile_e, const int* __restrict__ tile_p0,
                          const int* __restrict__ tile_end, const int* __restrict__ ntiles) {
    int ti = blockIdx.y;
    if (ti >= *ntiles) return;
    int e = tile_e[ti], p0 = tile_p0[ti], pend = tile_end[ti];
    int n0 = blockIdx.x * 64;

    __shared__ short Bg[64][KPAD];
    __shared__ short Bu[64][KPAD];

    int tid = threadIdx.x;
    int nl = tid & 63, kc = tid >> 6;          // staging role: n-lane, k-chunk of 8
    int lane = tid & 63, w = tid >> 6;         // compute role: wave w
    int col = lane & 15, quad = lane >> 4;

    const float* wgb = wg + (size_t)e * D_MODEL * D_FF + n0 + nl;
    const float* wub = wu + (size_t)e * D_MODEL * D_FF + n0 + nl;

    int row0 = p0 + w * 32 + col;      if (row0 > T_TOKENS - 1) row0 = T_TOKENS - 1;
    int row1 = row0 + 16;              if (row1 > T_TOKENS - 1) row1 = T_TOKENS - 1;
    const short* a0p = Xg + (size_t)row0 * D_MODEL + quad * 8;
    const short* a1p = Xg + (size_t)row1 * D_MODEL + quad * 8;

    f32x4 accg[2][4], accu[2][4];
#pragma unroll
    for (int m = 0; m < 2; ++m)
#pragma unroll
        for (int nf = 0; nf < 4; ++nf) {
            accg[m][nf] = (f32x4){0,0,0,0};
            accu[m][nf] = (f32x4){0,0,0,0};
        }

    for (int k0 = 0; k0 < D_MODEL; k0 += 32) {
        {   // stage W tiles (transpose fp32 [k][n] -> LDS bf16 [n][k])
            const float* g = wgb + (size_t)(k0 + kc * 8) * D_FF;
            const float* u = wub + (size_t)(k0 + kc * 8) * D_FF;
            float gv[8], uv[8];
#pragma unroll
            for (int j = 0; j < 8; ++j) {
                gv[j] = g[(size_t)j * D_FF];
                uv[j] = u[(size_t)j * D_FF];
            }
            uint4 pg, pu;
            pg.x = pack2bf(gv[0], gv[1]); pg.y = pack2bf(gv[2], gv[3]);
            pg.z = pack2bf(gv[4], gv[5]); pg.w = pack2bf(gv[6], gv[7]);
            pu.x = pack2bf(uv[0], uv[1]); pu.y = pack2bf(uv[2], uv[3]);
            pu.z = pack2bf(uv[4], uv[5]); pu.w = pack2bf(uv[6], uv[7]);
            *(uint4*)&Bg[nl][kc * 8] = pg;
            *(uint4*)&Bu[nl][kc * 8] = pu;
        }
        __syncthreads();
        bf16x8 a0 = *(const bf16x8*)(a0p + k0);
        bf16x8 a1 = *(const bf16x8*)(a1p + k0);
#pragma unroll
        for (int nf = 0; nf < 4; ++nf) {
            bf16x8 bg = *(const bf16x8*)&Bg[nf * 16 + col][quad * 8];
            bf16x8 bu = *(const bf16x8*)&Bu[nf * 16 + col][quad * 8];
            accg[0][nf] = __builtin_amdgcn_mfma_f32_16x16x32_bf16(a0, bg, accg[0][nf], 0, 0, 0);
            accg[1][nf] = __builtin_amdgcn_mfma_f32_16x16x32_bf16(a1, bg, accg[1][nf], 0, 0, 0);
            accu[0][nf] = __builtin_amdgcn_mfma_f32_16x16x32_bf16(a0, bu, accu[0][nf], 0, 0, 0);
            accu[1][nf] = __builtin_amdgcn_mfma_f32_16x16x32_bf16(a1, bu, accu[1][nf], 0, 0, 0);
        }
        __syncthreads();
    }

    // epilogue: h = silu(gate) * up, masked rows
#pragma unroll
    for (int m = 0; m < 2; ++m) {
#pragma unroll
        for (int r = 0; r < 4; ++r) {
            int mr = p0 + w * 32 + m * 16 + quad * 4 + r;
            if (mr < pend) {
#pragma unroll
                for (int nf = 0; nf < 4; ++nf) {
                    float gv = accg[m][nf][r], uv = accu[m][nf][r];
                    float hv = (gv / (1.f + __expf(-gv))) * uv;
                    h[(size_t)mr * D_FF + n0 + nf * 16 + col] = f2bf(hv);
                }
            }
        }
    }
}

// ---------------- GEMM2: out = h @ Wd, scatter rows ----------------
// grid: (D_MODEL/64, MAXT), block 256 (4 waves). Block tile: M=128, N=64, K=4096.

__launch_bounds__(256)
__global__ void moe_gemm2(const float* __restrict__ wd, const short* __restrict__ h,
                          const int* __restrict__ tok_of_row, float* __restrict__ out,
                          const int* __restrict__ tile_e, const int* __restrict__ tile_p0,
                          const int* __restrict__ tile_end, const int* __restrict__ ntiles) {
    int ti = blockIdx.y;
    if (ti >= *ntiles) return;
    int e = tile_e[ti], p0 = tile_p0[ti], pend = tile_end[ti];
    int d0 = blockIdx.x * 64;

    __shared__ short Bd[64][KPAD];

    int tid = threadIdx.x;
    int nl = tid & 63, kc = tid >> 6;
    int lane = tid & 63, w = tid >> 6;
    int col = lane & 15, quad = lane >> 4;

    const float* wb = wd + (size_t)e * D_FF * D_MODEL + d0 + nl;

    int row0 = p0 + w * 32 + col;      if (row0 > T_TOKENS - 1) row0 = T_TOKENS - 1;
    int row1 = row0 + 16;              if (row1 > T_TOKENS - 1) row1 = T_TOKENS - 1;
    const short* a0p = h + (size_t)row0 * D_FF + quad * 8;
    const short* a1p = h + (size_t)row1 * D_FF + quad * 8;

    f32x4 acc[2][4];
#pragma unroll
    for (int m = 0; m < 2; ++m)
#pragma unroll
        for (int nf = 0; nf < 4; ++nf) acc[m][nf] = (f32x4){0,0,0,0};

    for (int k0 = 0; k0 < D_FF; k0 += 32) {
        {
            const float* p = wb + (size_t)(k0 + kc * 8) * D_MODEL;
            float pv[8];
#pragma unroll
            for (int j = 0; j < 8; ++j) pv[j] = p[(size_t)j * D_MODEL];
            uint4 pk;
            pk.x = pack2bf(pv[0], pv[1]); pk.y = pack2bf(pv[2], pv[3]);
            pk.z = pack2bf(pv[4], pv[5]); pk.w = pack2bf(pv[6], pv[7]);
            *(uint4*)&Bd[nl][kc * 8] = pk;
        }
        __syncthreads();
        bf16x8 a0 = *(const bf16x8*)(a0p + k0);
        bf16x8 a1 = *(const bf16x8*)(a1p + k0);
#pragma unroll
        for (int nf = 0; nf < 4; ++nf) {
            bf16x8 b = *(const bf16x8*)&Bd[nf * 16 + col][quad * 8];
            acc[0][nf] = __builtin_amdgcn_mfma_f32_16x16x32_bf16(a0, b, acc[0][nf], 0, 0, 0);
            acc[1][nf] = __builtin_amdgcn_mfma_f32_16x16x32_bf16(a1, b, acc[1][nf], 0, 0, 0);
        }
        __syncthreads();
    }

#pragma unroll
    for (int m = 0; m < 2; ++m) {
#pragma unroll
        for (int r = 0; r < 4; ++r) {
            int mr = p0 + w * 32 + m * 16 + quad * 4 + r;
            if (mr < pend) {
                int t = tok_of_row[mr];
#pragma unroll
                for (int nf = 0; nf < 4; ++nf)
                    out[(size_t)t * D_MODEL + d0 + nf * 16 + col] = acc[m][nf][r];
            }
        }
    }
}

// ---------------- launch ----------------

extern "C" void kernel_launch(void* const* d_in, const int* in_sizes, int n_in,
                              void* d_out, int out_size, void* d_ws, size_t ws_size,
                              hipStream_t stream) {
    (void)in_sizes; (void)n_in; (void)out_size; (void)ws_size;
    const float* x   = (const float*)d_in[0];
    const int*   idx = (const int*)d_in[1];
    const float* wg  = (const float*)d_in[2];
    const float* wu  = (const float*)d_in[3];
    const float* wd  = (const float*)d_in[4];
    float* out = (float*)d_out;

    int* ws_i       = (int*)d_ws;
    int* counts     = ws_i;            // 8
    int* cursor     = ws_i + 8;        // 8
    int* offsets    = ws_i + 16;       // 9
    int* ntiles     = ws_i + 25;       // 1
    int* tile_e     = ws_i + 32;       // 24
    int* tile_p0    = ws_i + 104;      // 24
    int* tile_end   = ws_i + 176;      // 24
    int* tok_of_row = ws_i + 256;      // 2048

    short* Xg = (short*)((char*)d_ws + 16384);
    short* h  = (short*)((char*)d_ws + 16384 + (size_t)T_TOKENS * D_MODEL * 2);

    hipMemsetAsync(d_ws, 0, 1024, stream);
    moe_count<<<dim3((T_TOKENS + 255) / 256), 256, 0, stream>>>(idx, counts);
    moe_scan<<<dim3(1), 64, 0, stream>>>(counts, offsets, ntiles, tile_e, tile_p0, tile_end);
    moe_gather<<<dim3(T_TOKENS), 256, 0, stream>>>(x, idx, offsets, cursor, tok_of_row, Xg);
    moe_gemm1<<<dim3(D_FF / 64, MAXT), 256, 0, stream>>>(wg, wu, Xg, h,
                                                         tile_e, tile_p0, tile_end, ntiles);
    moe_gemm2<<<dim3(D_MODEL / 64, MAXT), 256, 0, stream>>>(wd, h, tok_of_row, out,
                                                            tile_e, tile_p0, tile_end, ntiles);
}

// Round 3
// 506.661 us; speedup vs baseline: 1.4208x; 1.1172x over previous
//
#include <hip/hip_runtime.h>
#include <hip/hip_bf16.h>
#include <stdint.h>

#define N_EXPERTS 8
#define D_MODEL   1024
#define D_FF      4096
#define T_TOKENS  2048
#define MT1       128
#define MAXT1     24      // sum ceil(c/128) <= 2048/128 + 8
#define MT2       64
#define MAXT2     40      // sum ceil(c/64)  <= 2048/64  + 8
#define BK        64
#define KP        72      // LDS k-stride (shorts): 144B rows, 16B aligned, 2-way banks

typedef __attribute__((ext_vector_type(8))) short bf16x8;
typedef __attribute__((ext_vector_type(4))) float f32x4;

__device__ __forceinline__ short f2bf(float f) {
    union { float f; uint32_t u; } v; v.f = f;
    uint32_t u = v.u;
    return (short)((u + 0x7fffu + ((u >> 16) & 1u)) >> 16);
}

__device__ __forceinline__ uint32_t pack2bf(float a, float b) {
    __hip_bfloat162 h = __float22bfloat162_rn(make_float2(a, b));
    return *(uint32_t*)&h;
}

template<int STRIDE>
__device__ __forceinline__ void ldw16(float v[16], const float* __restrict__ src) {
#pragma unroll
    for (int j = 0; j < 16; ++j) v[j] = src[(size_t)j * STRIDE];
}

__device__ __forceinline__ void stw16(short* dst, const float v[16]) {
    uint4 w0, w1;
    w0.x = pack2bf(v[0], v[1]);  w0.y = pack2bf(v[2], v[3]);
    w0.z = pack2bf(v[4], v[5]);  w0.w = pack2bf(v[6], v[7]);
    w1.x = pack2bf(v[8], v[9]);  w1.y = pack2bf(v[10], v[11]);
    w1.z = pack2bf(v[12], v[13]); w1.w = pack2bf(v[14], v[15]);
    *(uint4*)dst = w0;
    *(uint4*)(dst + 8) = w1;
}

// ---------------- routing: count + scan + tile tables in one kernel ----------------

__global__ void moe_route(const int* __restrict__ idx, int* __restrict__ offsets,
                          int* __restrict__ nt1p, int* __restrict__ t1_e,
                          int* __restrict__ t1_p0, int* __restrict__ t1_end,
                          int* __restrict__ nt2p, int* __restrict__ t2_e,
                          int* __restrict__ t2_p0, int* __restrict__ t2_end) {
    __shared__ int cnt[N_EXPERTS];
    int tid = threadIdx.x;
    if (tid < N_EXPERTS) cnt[tid] = 0;
    __syncthreads();
    for (int t = tid; t < T_TOKENS; t += 256) atomicAdd(&cnt[idx[t]], 1);
    __syncthreads();
    if (tid == 0) {
        int off = 0, nt1 = 0, nt2 = 0;
        for (int e = 0; e < N_EXPERTS; ++e) {
            offsets[e] = off;
            int c = cnt[e], end = off + c;
            for (int i = 0; i < c; i += MT1) { t1_e[nt1] = e; t1_p0[nt1] = off + i; t1_end[nt1] = end; ++nt1; }
            for (int i = 0; i < c; i += MT2) { t2_e[nt2] = e; t2_p0[nt2] = off + i; t2_end[nt2] = end; ++nt2; }
            off = end;
        }
        offsets[N_EXPERTS] = off;
        *nt1p = nt1;
        *nt2p = nt2;
    }
}

// one block per token: claim a permuted row slot, gather+convert x row to bf16
__global__ void moe_gather(const float* __restrict__ x, const int* __restrict__ idx,
                           const int* __restrict__ offsets, int* __restrict__ cursor,
                           int* __restrict__ tok_of_row, short* __restrict__ Xg) {
    __shared__ int sp;
    int t = blockIdx.x;
    if (threadIdx.x == 0) {
        int e = idx[t];
        int p = offsets[e] + atomicAdd(&cursor[e], 1);
        tok_of_row[p] = t;
        sp = p;
    }
    __syncthreads();
    int p = sp;
    const float4* src = (const float4*)(x + (size_t)t * D_MODEL);
    uint2* dst = (uint2*)(Xg + (size_t)p * D_MODEL);
    int i = threadIdx.x;                       // D_MODEL/4 == 256 == blockDim
    float4 v = src[i];
    uint2 o;
    o.x = pack2bf(v.x, v.y);
    o.y = pack2bf(v.z, v.w);
    dst[i] = o;
}

// ---------------- GEMM1: gate/up + SwiGLU -> h (bf16) ----------------
// grid (D_FF/64, MAXT1), block 256. Tile M=128 N=64 BK=64.
// Pipelined: issue loads for k+BK -> MFMA on LDS buf p -> cvt+write buf p^1 -> barrier.

__launch_bounds__(256)
__global__ void moe_gemm1(const float* __restrict__ wg, const float* __restrict__ wu,
                          const short* __restrict__ Xg, short* __restrict__ h,
                          const int* __restrict__ tile_e, const int* __restrict__ tile_p0,
                          const int* __restrict__ tile_end, const int* __restrict__ ntiles) {
    int ti = blockIdx.y;
    if (ti >= *ntiles) return;
    int e = tile_e[ti], p0 = tile_p0[ti], pend = tile_end[ti];
    int n0 = blockIdx.x * 64;

    __shared__ short Bg[2][64][KP];
    __shared__ short Bu[2][64][KP];

    int tid = threadIdx.x;
    int nl = tid & 63, kc = tid >> 6;          // staging: n-lane, k-chunk of 16
    int lane = tid & 63, w = tid >> 6;         // compute: wave id
    int col = lane & 15, quad = lane >> 4;

    const float* wgb = wg + (size_t)e * D_MODEL * D_FF + (size_t)(kc * 16) * D_FF + n0 + nl;
    const float* wub = wu + (size_t)e * D_MODEL * D_FF + (size_t)(kc * 16) * D_FF + n0 + nl;

    int row0 = p0 + w * 32 + col;      if (row0 > T_TOKENS - 1) row0 = T_TOKENS - 1;
    int row1 = row0 + 16;              if (row1 > T_TOKENS - 1) row1 = T_TOKENS - 1;
    const short* a0p = Xg + (size_t)row0 * D_MODEL + quad * 8;
    const short* a1p = Xg + (size_t)row1 * D_MODEL + quad * 8;

    f32x4 accg[2][4], accu[2][4];
#pragma unroll
    for (int m = 0; m < 2; ++m)
#pragma unroll
        for (int nf = 0; nf < 4; ++nf) {
            accg[m][nf] = (f32x4){0,0,0,0};
            accu[m][nf] = (f32x4){0,0,0,0};
        }

    // prologue: stage k=0
    {
        float g0[16], u0[16];
        ldw16<D_FF>(g0, wgb);
        ldw16<D_FF>(u0, wub);
        stw16(&Bg[0][nl][kc * 16], g0);
        stw16(&Bu[0][nl][kc * 16], u0);
    }
    __syncthreads();

    bf16x8 a00 = *(const bf16x8*)(a0p);
    bf16x8 a01 = *(const bf16x8*)(a0p + 32);
    bf16x8 a10 = *(const bf16x8*)(a1p);
    bf16x8 a11 = *(const bf16x8*)(a1p + 32);

    const int NIT = D_MODEL / BK;   // 16
    int p = 0;
#pragma unroll 1
    for (int it = 0; it < NIT; ++it) {
        int kn = (it + 1 == NIT) ? 0 : (it + 1) * BK;   // wrapped prefetch on last iter
        float gn[16], un[16];
        ldw16<D_FF>(gn, wgb + (size_t)kn * D_FF);
        ldw16<D_FF>(un, wub + (size_t)kn * D_FF);
        bf16x8 a00n = *(const bf16x8*)(a0p + kn);
        bf16x8 a01n = *(const bf16x8*)(a0p + kn + 32);
        bf16x8 a10n = *(const bf16x8*)(a1p + kn);
        bf16x8 a11n = *(const bf16x8*)(a1p + kn + 32);

#pragma unroll
        for (int nf = 0; nf < 4; ++nf) {
            bf16x8 bg0 = *(const bf16x8*)&Bg[p][nf * 16 + col][quad * 8];
            bf16x8 bg1 = *(const bf16x8*)&Bg[p][nf * 16 + col][32 + quad * 8];
            bf16x8 bu0 = *(const bf16x8*)&Bu[p][nf * 16 + col][quad * 8];
            bf16x8 bu1 = *(const bf16x8*)&Bu[p][nf * 16 + col][32 + quad * 8];
            accg[0][nf] = __builtin_amdgcn_mfma_f32_16x16x32_bf16(a00, bg0, accg[0][nf], 0, 0, 0);
            accg[0][nf] = __builtin_amdgcn_mfma_f32_16x16x32_bf16(a01, bg1, accg[0][nf], 0, 0, 0);
            accg[1][nf] = __builtin_amdgcn_mfma_f32_16x16x32_bf16(a10, bg0, accg[1][nf], 0, 0, 0);
            accg[1][nf] = __builtin_amdgcn_mfma_f32_16x16x32_bf16(a11, bg1, accg[1][nf], 0, 0, 0);
            accu[0][nf] = __builtin_amdgcn_mfma_f32_16x16x32_bf16(a00, bu0, accu[0][nf], 0, 0, 0);
            accu[0][nf] = __builtin_amdgcn_mfma_f32_16x16x32_bf16(a01, bu1, accu[0][nf], 0, 0, 0);
            accu[1][nf] = __builtin_amdgcn_mfma_f32_16x16x32_bf16(a10, bu0, accu[1][nf], 0, 0, 0);
            accu[1][nf] = __builtin_amdgcn_mfma_f32_16x16x32_bf16(a11, bu1, accu[1][nf], 0, 0, 0);
        }

        stw16(&Bg[p ^ 1][nl][kc * 16], gn);
        stw16(&Bu[p ^ 1][nl][kc * 16], un);
        a00 = a00n; a01 = a01n; a10 = a10n; a11 = a11n;
        __syncthreads();
        p ^= 1;
    }

    // epilogue: h = silu(gate) * up, masked rows
#pragma unroll
    for (int m = 0; m < 2; ++m) {
#pragma unroll
        for (int r = 0; r < 4; ++r) {
            int mr = p0 + w * 32 + m * 16 + quad * 4 + r;
            if (mr < pend) {
#pragma unroll
                for (int nf = 0; nf < 4; ++nf) {
                    float gv = accg[m][nf][r], uv = accu[m][nf][r];
                    float hv = (gv / (1.f + __expf(-gv))) * uv;
                    h[(size_t)mr * D_FF + n0 + nf * 16 + col] = f2bf(hv);
                }
            }
        }
    }
}

// ---------------- GEMM2: out = h @ Wd, scatter rows ----------------
// grid (D_MODEL/64, MAXT2), block 256. Tile M=64 N=64 BK=64; wave w owns rows [16w,16w+16).

__launch_bounds__(256)
__global__ void moe_gemm2(const float* __restrict__ wd, const short* __restrict__ h,
                          const int* __restrict__ tok_of_row, float* __restrict__ out,
                          const int* __restrict__ tile_e, const int* __restrict__ tile_p0,
                          const int* __restrict__ tile_end, const int* __restrict__ ntiles) {
    int ti = blockIdx.y;
    if (ti >= *ntiles) return;
    int e = tile_e[ti], p0 = tile_p0[ti], pend = tile_end[ti];
    int d0 = blockIdx.x * 64;

    __shared__ short Bd[2][64][KP];

    int tid = threadIdx.x;
    int nl = tid & 63, kc = tid >> 6;
    int lane = tid & 63, w = tid >> 6;
    int col = lane & 15, quad = lane >> 4;

    const float* wb = wd + (size_t)e * D_FF * D_MODEL + (size_t)(kc * 16) * D_MODEL + d0 + nl;

    int row0 = p0 + w * 16 + col;      if (row0 > T_TOKENS - 1) row0 = T_TOKENS - 1;
    const short* a0p = h + (size_t)row0 * D_FF + quad * 8;

    f32x4 acc[4];
#pragma unroll
    for (int nf = 0; nf < 4; ++nf) acc[nf] = (f32x4){0,0,0,0};

    {
        float w0[16];
        ldw16<D_MODEL>(w0, wb);
        stw16(&Bd[0][nl][kc * 16], w0);
    }
    __syncthreads();

    bf16x8 a0 = *(const bf16x8*)(a0p);
    bf16x8 a1 = *(const bf16x8*)(a0p + 32);

    const int NIT = D_FF / BK;   // 64
    int p = 0;
#pragma unroll 1
    for (int it = 0; it < NIT; ++it) {
        int kn = (it + 1 == NIT) ? 0 : (it + 1) * BK;
        float wn[16];
        ldw16<D_MODEL>(wn, wb + (size_t)kn * D_MODEL);
        bf16x8 a0n = *(const bf16x8*)(a0p + kn);
        bf16x8 a1n = *(const bf16x8*)(a0p + kn + 32);

#pragma unroll
        for (int nf = 0; nf < 4; ++nf) {
            bf16x8 b0 = *(const bf16x8*)&Bd[p][nf * 16 + col][quad * 8];
            bf16x8 b1 = *(const bf16x8*)&Bd[p][nf * 16 + col][32 + quad * 8];
            acc[nf] = __builtin_amdgcn_mfma_f32_16x16x32_bf16(a0, b0, acc[nf], 0, 0, 0);
            acc[nf] = __builtin_amdgcn_mfma_f32_16x16x32_bf16(a1, b1, acc[nf], 0, 0, 0);
        }

        stw16(&Bd[p ^ 1][nl][kc * 16], wn);
        a0 = a0n; a1 = a1n;
        __syncthreads();
        p ^= 1;
    }

#pragma unroll
    for (int r = 0; r < 4; ++r) {
        int mr = p0 + w * 16 + quad * 4 + r;
        if (mr < pend) {
            int t = tok_of_row[mr];
#pragma unroll
            for (int nf = 0; nf < 4; ++nf)
                out[(size_t)t * D_MODEL + d0 + nf * 16 + col] = acc[nf][r];
        }
    }
}

// ---------------- launch ----------------

extern "C" void kernel_launch(void* const* d_in, const int* in_sizes, int n_in,
                              void* d_out, int out_size, void* d_ws, size_t ws_size,
                              hipStream_t stream) {
    (void)in_sizes; (void)n_in; (void)out_size; (void)ws_size;
    const float* x   = (const float*)d_in[0];
    const int*   idx = (const int*)d_in[1];
    const float* wg  = (const float*)d_in[2];
    const float* wu  = (const float*)d_in[3];
    const float* wd  = (const float*)d_in[4];
    float* out = (float*)d_out;

    int* ws_i       = (int*)d_ws;
    int* cursor     = ws_i;            // 8   (memset to 0)
    int* offsets    = ws_i + 8;        // 9
    int* nt1        = ws_i + 20;       // 1
    int* nt2        = ws_i + 21;       // 1
    int* t1_e       = ws_i + 32;       // 24
    int* t1_p0      = ws_i + 56;       // 24
    int* t1_end     = ws_i + 80;       // 24
    int* t2_e       = ws_i + 104;      // 40
    int* t2_p0      = ws_i + 144;      // 40
    int* t2_end     = ws_i + 184;      // 40
    int* tok_of_row = ws_i + 256;      // 2048

    short* Xg = (short*)((char*)d_ws + 16384);
    short* h  = (short*)((char*)d_ws + 16384 + (size_t)T_TOKENS * D_MODEL * 2);

    hipMemsetAsync(d_ws, 0, 128, stream);
    moe_route<<<dim3(1), 256, 0, stream>>>(idx, offsets, nt1, t1_e, t1_p0, t1_end,
                                           nt2, t2_e, t2_p0, t2_end);
    moe_gather<<<dim3(T_TOKENS), 256, 0, stream>>>(x, idx, offsets, cursor, tok_of_row, Xg);
    moe_gemm1<<<dim3(D_FF / 64, MAXT1), 256, 0, stream>>>(wg, wu, Xg, h,
                                                          t1_e, t1_p0, t1_end, nt1);
    moe_gemm2<<<dim3(D_MODEL / 64, MAXT2), 256, 0, stream>>>(wd, h, tok_of_row, out,
                                                             t2_e, t2_p0, t2_end, nt2);
}